// Round 1
// baseline (159.846 us; speedup 1.0000x reference)
//
#include <hip/hip_runtime.h>

// LengthRegulator: out[b,pos,:] = x[b, src(b,pos), :] masked by pos < total[b]
// B=16, T=1024, D=512, MAXLEN=4096 (fixed by setup_inputs()).

#define BB 16
#define TT 1024
#define DD 512
#define MAXLEN 4096

// ---------------------------------------------------------------------------
// Kernel 1: per-batch cumsum of clamped durations + build inverse src table.
// One block per batch, 256 threads, each thread owns 4 contiguous t's.
// srcTab[b*MAXLEN + pos] = t such that csum[t-1] <= pos < csum[t], or -1 if
// pos >= total[b].
// ---------------------------------------------------------------------------
__global__ __launch_bounds__(256) void build_src_kernel(
    const int* __restrict__ dur, int* __restrict__ srcTab) {
  const int b = blockIdx.x;
  const int tid = threadIdx.x;

  __shared__ int lds[256];
  __shared__ int s_total;

  const int t0 = tid * 4;
  const int* dp = dur + b * TT + t0;
  int d0 = max(dp[0], 0);
  int d1 = max(dp[1], 0);
  int d2 = max(dp[2], 0);
  int d3 = max(dp[3], 0);
  // local inclusive scan of the 4-element chunk
  const int s1 = d0 + d1;
  const int s2 = s1 + d2;
  const int s3 = s2 + d3;

  lds[tid] = s3;
  __syncthreads();

  // Hillis-Steele inclusive scan over the 256 chunk sums
  int val = s3;
  for (int off = 1; off < 256; off <<= 1) {
    int other = (tid >= off) ? lds[tid - off] : 0;
    __syncthreads();
    val += other;
    lds[tid] = val;
    __syncthreads();
  }
  const int incl = val;        // inclusive csum through t0+3
  const int excl = incl - s3;  // csum before t0

  if (tid == 255) s_total = incl;
  __syncthreads();
  const int total = s_total;

  // scatter the inverse map: run of length d_j gets value t0+j
  int c[4] = {excl + d0, excl + s1, excl + s2, excl + s3};
  int dd4[4] = {d0, d1, d2, d3};
  int* st = srcTab + b * MAXLEN;
#pragma unroll
  for (int j = 0; j < 4; ++j) {
    const int end = c[j];
    for (int p = end - dd4[j]; p < end; ++p) st[p] = t0 + j;
  }
  // tail: masked region -> -1
  for (int p = total + tid; p < MAXLEN; p += 256) st[p] = -1;
}

// ---------------------------------------------------------------------------
// Kernel 2: one wave (64 lanes) per output row of 512 floats (128 float4).
// Lane i copies float4 i and i+64. 4 waves per 256-thread block.
// ---------------------------------------------------------------------------
__global__ __launch_bounds__(256) void gather_kernel(
    const float4* __restrict__ x, const int* __restrict__ srcTab,
    float4* __restrict__ out) {
  const int wave = (int)((blockIdx.x * 256u + threadIdx.x) >> 6);
  const int lane = threadIdx.x & 63;
  const int row = wave;            // [0, BB*MAXLEN)
  const int b = row >> 12;         // row / MAXLEN
  const int src = srcTab[row];     // wave-uniform broadcast load

  float4* op = out + (size_t)row * (DD / 4);
  if (src < 0) {
    const float4 z = {0.f, 0.f, 0.f, 0.f};
    op[lane] = z;
    op[lane + 64] = z;
  } else {
    const float4* ip = x + ((size_t)b * TT + (size_t)src) * (DD / 4);
    op[lane] = ip[lane];
    op[lane + 64] = ip[lane + 64];
  }
}

extern "C" void kernel_launch(void* const* d_in, const int* in_sizes, int n_in,
                              void* d_out, int out_size, void* d_ws,
                              size_t ws_size, hipStream_t stream) {
  const float* x = (const float*)d_in[0];
  const int* dur = (const int*)d_in[1];
  int* srcTab = (int*)d_ws;  // BB*MAXLEN ints = 256 KiB

  build_src_kernel<<<BB, 256, 0, stream>>>(dur, srcTab);

  const int rows = BB * MAXLEN;          // 65536 rows
  gather_kernel<<<rows / 4, 256, 0, stream>>>((const float4*)x, srcTab,
                                              (float4*)d_out);
}